// Round 8
// baseline (149.534 us; speedup 1.0000x reference)
//
#include <hip/hip_runtime.h>
#include <hip/hip_bf16.h>

#define BB 16
#define NQ 64
#define NK 512
#define HD 256   // H = QS = KS = VD = 256

typedef __attribute__((ext_vector_type(8))) short short8;
typedef __attribute__((ext_vector_type(4))) float f32x4;

__device__ __forceinline__ ushort bf16_rne(float v) {
    unsigned u = __float_as_uint(v);
    return (ushort)((u + 0x7FFFu + ((u >> 16) & 1u)) >> 16);
}
__device__ __forceinline__ float bf16_to_f(ushort h) {
    return __uint_as_float(((unsigned)h) << 16);
}

// ---------------------------------------------------------------------------
// One-shot conversion: q/k fp32 -> hi/lo bf16; W [k][n] -> hi/lo bf16 [n][k].
// ---------------------------------------------------------------------------
__global__ __launch_bounds__(256) void convert_split(
    const float* __restrict__ q, const float* __restrict__ k,
    const float* __restrict__ wq, const float* __restrict__ wk,
    ushort* __restrict__ qh, ushort* __restrict__ ql,
    ushort* __restrict__ kh, ushort* __restrict__ kl,
    ushort* __restrict__ wqh, ushort* __restrict__ wql,
    ushort* __restrict__ wkh, ushort* __restrict__ wkl)
{
    const int idx = blockIdx.x * 256 + threadIdx.x;
    if (blockIdx.x < 2304) {
        int e = idx * 4;
        const float* src; ushort *dh, *dl; int off;
        if (e < 1024 * 256) { src = q; dh = qh; dl = ql; off = e; }
        else { src = k; dh = kh; dl = kl; off = e - 1024 * 256; }
        float4 v = *(const float4*)&src[off];
        float fv[4] = {v.x, v.y, v.z, v.w};
        ushort hh[4], ll[4];
        #pragma unroll
        for (int c = 0; c < 4; ++c) {
            hh[c] = bf16_rne(fv[c]);
            ll[c] = bf16_rne(fv[c] - bf16_to_f(hh[c]));
        }
        *(ushort4*)&dh[off] = make_ushort4(hh[0], hh[1], hh[2], hh[3]);
        *(ushort4*)&dl[off] = make_ushort4(ll[0], ll[1], ll[2], ll[3]);
    } else {
        int widx = idx - 2304 * 256;
        const float* W; ushort *wh, *wl;
        if (widx < 16384) { W = wq; wh = wqh; wl = wql; }
        else { W = wk; wh = wkh; wl = wkl; widx -= 16384; }
        int n  = widx >> 6;
        int k4 = (widx & 63) * 4;
        ushort hh[4], ll[4];
        #pragma unroll
        for (int c = 0; c < 4; ++c) {
            float v = W[(k4 + c) * 256 + n];
            hh[c] = bf16_rne(v);
            ll[c] = bf16_rne(v - bf16_to_f(hh[c]));
        }
        *(ushort4*)&wh[n * 256 + k4] = make_ushort4(hh[0], hh[1], hh[2], hh[3]);
        *(ushort4*)&wl[n * 256 + k4] = make_ushort4(ll[0], ll[1], ll[2], ll[3]);
    }
}

// ---------------------------------------------------------------------------
// Split-bf16 MFMA GEMM: C = A@W (AhWh + AlWh + AhWl), * scale.  128x64 tile,
// BK=64, XOR-swizzled LDS, product-major MFMA, next-tile register prefetch.
// ---------------------------------------------------------------------------
__global__ __launch_bounds__(256, 2) void proj_mfma2(
    const ushort* __restrict__ qh, const ushort* __restrict__ ql,
    const ushort* __restrict__ kh, const ushort* __restrict__ kl,
    const ushort* __restrict__ wqh, const ushort* __restrict__ wql,
    const ushort* __restrict__ wkh, const ushort* __restrict__ wkl,
    float* __restrict__ qp, float* __restrict__ kp, float scale)
{
    __shared__ ushort AsH[128 * 64], AsL[128 * 64];
    __shared__ ushort BsH[64 * 64],  BsL[64 * 64];

    const ushort *Ah, *Al, *Bh, *Bl; float* C; int rows0;
    if (blockIdx.x < 8) { Ah = qh; Al = ql; Bh = wqh; Bl = wql; C = qp; rows0 = blockIdx.x * 128; }
    else                { Ah = kh; Al = kl; Bh = wkh; Bl = wkl; C = kp; rows0 = (blockIdx.x - 8) * 128; }
    const int cols0 = blockIdx.y * 64;

    const int t = threadIdx.x, lane = t & 63, wave = t >> 6;
    const int quad = lane >> 4, l15 = lane & 15;
    const int lr = lane >> 3;
    const int cg = (lane & 7) ^ lr;
    const int swz0 = quad ^ (l15 & 7);
    const int swz1 = (quad + 4) ^ (l15 & 7);

    f32x4 acc[2][4];
    #pragma unroll
    for (int i = 0; i < 2; ++i)
        #pragma unroll
        for (int j = 0; j < 4; ++j)
            acc[i][j] = (f32x4){0.f, 0.f, 0.f, 0.f};

    short8 rAh[4], rAl[4], rBh[2], rBl[2];
    #pragma unroll
    for (int i = 0; i < 4; ++i) {
        size_t g = (size_t)(rows0 + (wave * 4 + i) * 8 + lr) * 256 + cg * 8;
        rAh[i] = *(const short8*)&Ah[g];
        rAl[i] = *(const short8*)&Al[g];
    }
    #pragma unroll
    for (int j = 0; j < 2; ++j) {
        size_t g = (size_t)(cols0 + (wave * 2 + j) * 8 + lr) * 256 + cg * 8;
        rBh[j] = *(const short8*)&Bh[g];
        rBl[j] = *(const short8*)&Bl[g];
    }

    for (int k0 = 0; k0 < 256; k0 += 64) {
        __syncthreads();
        #pragma unroll
        for (int i = 0; i < 4; ++i) {
            int ci = (wave * 4 + i) * 64 + lane;
            *(short8*)&AsH[ci * 8] = rAh[i];
            *(short8*)&AsL[ci * 8] = rAl[i];
        }
        #pragma unroll
        for (int j = 0; j < 2; ++j) {
            int ci = (wave * 2 + j) * 64 + lane;
            *(short8*)&BsH[ci * 8] = rBh[j];
            *(short8*)&BsL[ci * 8] = rBl[j];
        }
        __syncthreads();

        if (k0 + 64 < 256) {
            #pragma unroll
            for (int i = 0; i < 4; ++i) {
                size_t g = (size_t)(rows0 + (wave * 4 + i) * 8 + lr) * 256 + k0 + 64 + cg * 8;
                rAh[i] = *(const short8*)&Ah[g];
                rAl[i] = *(const short8*)&Al[g];
            }
            #pragma unroll
            for (int j = 0; j < 2; ++j) {
                size_t g = (size_t)(cols0 + (wave * 2 + j) * 8 + lr) * 256 + k0 + 64 + cg * 8;
                rBh[j] = *(const short8*)&Bh[g];
                rBl[j] = *(const short8*)&Bl[g];
            }
        }

        #pragma unroll
        for (int ks = 0; ks < 2; ++ks) {
            const int s = ks ? swz1 : swz0;
            short8 aH[2], aL[2], bH[4], bL[4];
            #pragma unroll
            for (int ms = 0; ms < 2; ++ms) {
                int r = wave * 32 + ms * 16 + l15;
                aH[ms] = *(const short8*)&AsH[r * 64 + s * 8];
                aL[ms] = *(const short8*)&AsL[r * 64 + s * 8];
            }
            #pragma unroll
            for (int ns = 0; ns < 4; ++ns) {
                int n = ns * 16 + l15;
                bH[ns] = *(const short8*)&BsH[n * 64 + s * 8];
                bL[ns] = *(const short8*)&BsL[n * 64 + s * 8];
            }
            #pragma unroll
            for (int ms = 0; ms < 2; ++ms)
                #pragma unroll
                for (int ns = 0; ns < 4; ++ns)
                    acc[ms][ns] = __builtin_amdgcn_mfma_f32_16x16x32_bf16(aH[ms], bH[ns], acc[ms][ns], 0, 0, 0);
            #pragma unroll
            for (int ms = 0; ms < 2; ++ms)
                #pragma unroll
                for (int ns = 0; ns < 4; ++ns)
                    acc[ms][ns] = __builtin_amdgcn_mfma_f32_16x16x32_bf16(aL[ms], bH[ns], acc[ms][ns], 0, 0, 0);
            #pragma unroll
            for (int ms = 0; ms < 2; ++ms)
                #pragma unroll
                for (int ns = 0; ns < 4; ++ns)
                    acc[ms][ns] = __builtin_amdgcn_mfma_f32_16x16x32_bf16(aH[ms], bL[ns], acc[ms][ns], 0, 0, 0);
        }
    }

    #pragma unroll
    for (int ms = 0; ms < 2; ++ms) {
        int rbase = rows0 + wave * 32 + ms * 16 + quad * 4;
        #pragma unroll
        for (int ns = 0; ns < 4; ++ns) {
            int col = cols0 + ns * 16 + l15;
            #pragma unroll
            for (int r = 0; r < 4; ++r)
                C[(size_t)(rbase + r) * 256 + col] = acc[ms][ns][r] * scale;
        }
    }
}

// ---------------------------------------------------------------------------
// Flash-style partial: block = (b, 16-key chunk).  512 blocks, alive ~256,
// UNIFORM cost.  Stages 16 k-rows + 16 V-rows + w into LDS once; streams all
// 64 q-rows in 4 groups.  lane=(q,k) computes one full 256-h tanh score from
// LDS; per-chunk softmax (m_loc, l_loc, P=exp(s-m_loc)); P@V into 64 regs.
// Masked keys (kglob >= vl): s=-1e6 -> exp2 underflows to exactly 0.
// score = Wsum - 2*sum_h w*rcp(exp2(q+k)+1), inputs pre-scaled by 2/ln2.
// ---------------------------------------------------------------------------
__global__ __launch_bounds__(256) void score_pv_partial(
    const float* __restrict__ qp,      // [B*NQ, H] pre-scaled
    const float* __restrict__ kp,      // [B*NK, H] pre-scaled
    const float* __restrict__ values,  // [B, NK, VD]
    const int*   __restrict__ vlens,   // [B]
    const float* __restrict__ w_v,     // [H]
    float* __restrict__ pO,            // [B][32][64][256]
    float* __restrict__ pM,            // [B][32][64]
    float* __restrict__ pL)            // [B][32][64]
{
    __shared__ float ks[16][260];
    __shared__ float vs_[16][260];
    __shared__ float qs[16][260];
    __shared__ float wv[HD];
    __shared__ float Ps[64][20];
    __shared__ float msub[64], lsub[64];

    const int b     = blockIdx.x >> 5;
    const int chunk = blockIdx.x & 31;
    const int vl    = vlens[b];
    if (chunk * 16 >= vl) return;

    const int t    = threadIdx.x;
    const int lane = t & 63;

    // stage k-chunk, V-chunk, w
    const float* kbase = kp + ((size_t)b * NK + chunk * 16) * HD;
    const float* vbase = values + ((size_t)b * NK + chunk * 16) * HD;
    #pragma unroll
    for (int i = 0; i < 4; ++i) {
        int idx = i * 256 + t;
        int row = idx >> 6, c4 = (idx & 63) * 4;
        *(float4*)&ks[row][c4]  = *(const float4*)&kbase[(size_t)row * HD + c4];
        *(float4*)&vs_[row][c4] = *(const float4*)&vbase[(size_t)row * HD + c4];
    }
    if (t < 64) *(float4*)&wv[t * 4] = *(const float4*)&w_v[t * 4];
    __syncthreads();

    float Wsum;
    {
        float ws = wv[lane] + wv[lane + 64] + wv[lane + 128] + wv[lane + 192];
        #pragma unroll
        for (int off = 32; off; off >>= 1) ws += __shfl_xor(ws, off);
        Wsum = ws;
    }

    const int qloc = t >> 4;     // 0..15 within group
    const int kl   = t & 15;
    const float L2E = 1.4426950408889634f;
    const bool masked = (chunk * 16 + kl >= vl);

    for (int g = 0; g < 4; ++g) {
        // stage q-group
        const float* qsrc = qp + ((size_t)b * NQ + g * 16) * HD;
        #pragma unroll
        for (int i = 0; i < 4; ++i) {
            int idx = i * 256 + t;
            int row = idx >> 6, c4 = (idx & 63) * 4;
            *(float4*)&qs[row][c4] = *(const float4*)&qsrc[(size_t)row * HD + c4];
        }
        __syncthreads();

        const float* qrow = &qs[qloc][0];
        const float* krow = &ks[kl][0];
        float s0 = 0.f, s1 = 0.f;
        #pragma unroll 4
        for (int h8 = 0; h8 < 32; ++h8) {
            float4 qa = *(const float4*)&qrow[h8 * 8];
            float4 qb = *(const float4*)&qrow[h8 * 8 + 4];
            float4 ka = *(const float4*)&krow[h8 * 8];
            float4 kb = *(const float4*)&krow[h8 * 8 + 4];
            float4 wa = *(const float4*)&wv[h8 * 8];
            float4 wb = *(const float4*)&wv[h8 * 8 + 4];
            s0 = fmaf(wa.x, __builtin_amdgcn_rcpf(__builtin_amdgcn_exp2f(qa.x + ka.x) + 1.f), s0);
            s0 = fmaf(wa.y, __builtin_amdgcn_rcpf(__builtin_amdgcn_exp2f(qa.y + ka.y) + 1.f), s0);
            s0 = fmaf(wa.z, __builtin_amdgcn_rcpf(__builtin_amdgcn_exp2f(qa.z + ka.z) + 1.f), s0);
            s0 = fmaf(wa.w, __builtin_amdgcn_rcpf(__builtin_amdgcn_exp2f(qa.w + ka.w) + 1.f), s0);
            s1 = fmaf(wb.x, __builtin_amdgcn_rcpf(__builtin_amdgcn_exp2f(qb.x + kb.x) + 1.f), s1);
            s1 = fmaf(wb.y, __builtin_amdgcn_rcpf(__builtin_amdgcn_exp2f(qb.y + kb.y) + 1.f), s1);
            s1 = fmaf(wb.z, __builtin_amdgcn_rcpf(__builtin_amdgcn_exp2f(qb.z + kb.z) + 1.f), s1);
            s1 = fmaf(wb.w, __builtin_amdgcn_rcpf(__builtin_amdgcn_exp2f(qb.w + kb.w) + 1.f), s1);
        }
        float s = fmaf(-2.f, s0 + s1, Wsum);
        if (masked) s = -1e6f;

        // local max / expsum over the 16 k-lanes (low 4 lane bits)
        float m = s;
        m = fmaxf(m, __shfl_xor(m, 8));
        m = fmaxf(m, __shfl_xor(m, 4));
        m = fmaxf(m, __shfl_xor(m, 2));
        m = fmaxf(m, __shfl_xor(m, 1));
        float e = __builtin_amdgcn_exp2f((s - m) * L2E);
        float l = e;
        l += __shfl_xor(l, 8);
        l += __shfl_xor(l, 4);
        l += __shfl_xor(l, 2);
        l += __shfl_xor(l, 1);
        Ps[g * 16 + qloc][kl] = e;
        if (kl == 0) { msub[g * 16 + qloc] = m; lsub[g * 16 + qloc] = l; }
        __syncthreads();   // qs/Ps consistency before next group
    }

    // ---- PV: lane owns (q = t>>2, vd = (t&3)*4 + rep*16) ----
    const int qg = t >> 2;
    const int c  = (t & 3) * 4;
    f32x4 acc[16];
    #pragma unroll
    for (int r = 0; r < 16; ++r) acc[r] = (f32x4){0.f, 0.f, 0.f, 0.f};

    #pragma unroll
    for (int k = 0; k < 16; ++k) {
        float p = Ps[qg][k];
        #pragma unroll
        for (int r = 0; r < 16; ++r) {
            float4 v = *(const float4*)&vs_[k][c + r * 16];
            acc[r][0] = fmaf(p, v.x, acc[r][0]);
            acc[r][1] = fmaf(p, v.y, acc[r][1]);
            acc[r][2] = fmaf(p, v.z, acc[r][2]);
            acc[r][3] = fmaf(p, v.w, acc[r][3]);
        }
    }
    float* obase = pO + (((size_t)(b * 32 + chunk)) * 64 + qg) * 256;
    #pragma unroll
    for (int r = 0; r < 16; ++r)
        *(f32x4*)&obase[c + r * 16] = acc[r];
    if ((t & 3) == 0) {
        pM[(size_t)(b * 32 + chunk) * 64 + qg] = msub[qg];
        pL[(size_t)(b * 32 + chunk) * 64 + qg] = lsub[qg];
    }
}

// ---------------------------------------------------------------------------
// Combine: block per (b,q), 64 threads.  O = sum_i e2(m_i-m)*O_i / sum_i
// e2(m_i-m)*l_i over alive chunks i < nc.
// ---------------------------------------------------------------------------
__global__ __launch_bounds__(64) void combine_pv(
    const float* __restrict__ pO, const float* __restrict__ pM,
    const float* __restrict__ pL, const int* __restrict__ vlens,
    float* __restrict__ out)
{
    const int b    = blockIdx.x >> 6;
    const int q    = blockIdx.x & 63;
    const int lane = threadIdx.x;
    const int vl   = vlens[b];
    const int nc   = (vl + 15) >> 4;
    const float L2E = 1.4426950408889634f;

    float mi = -3e38f, li = 0.f;
    if (lane < nc) {
        mi = pM[(size_t)(b * 32 + lane) * 64 + q];
        li = pL[(size_t)(b * 32 + lane) * 64 + q];
    }
    float m = mi;
    #pragma unroll
    for (int off = 32; off; off >>= 1) m = fmaxf(m, __shfl_xor(m, off));
    float we = __builtin_amdgcn_exp2f((mi - m) * L2E);
    float w  = li * we;
    float L  = w;
    #pragma unroll
    for (int off = 32; off; off >>= 1) L += __shfl_xor(L, off);

    f32x4 acc = (f32x4){0.f, 0.f, 0.f, 0.f};
    for (int i = 0; i < nc; ++i) {
        float wi = __shfl(we, i);
        float4 v = *(const float4*)&pO[(((size_t)(b * 32 + i)) * 64 + q) * 256 + lane * 4];
        acc[0] = fmaf(wi, v.x, acc[0]);
        acc[1] = fmaf(wi, v.y, acc[1]);
        acc[2] = fmaf(wi, v.z, acc[2]);
        acc[3] = fmaf(wi, v.w, acc[3]);
    }
    const float inv = __builtin_amdgcn_rcpf(L);
    float4 o;
    o.x = acc[0] * inv; o.y = acc[1] * inv; o.z = acc[2] * inv; o.w = acc[3] * inv;
    *(float4*)&out[((size_t)(b * 64 + q)) * 256 + lane * 4] = o;
}

extern "C" void kernel_launch(void* const* d_in, const int* in_sizes, int n_in,
                              void* d_out, int out_size, void* d_ws, size_t ws_size,
                              hipStream_t stream) {
    const float* queries = (const float*)d_in[0];
    const float* keys    = (const float*)d_in[1];
    const float* values  = (const float*)d_in[2];
    const int*   vlens   = (const int*)d_in[3];
    const float* W_q     = (const float*)d_in[4];
    const float* W_k     = (const float*)d_in[5];
    const float* w_v     = (const float*)d_in[6];
    float* out = (float*)d_out;

    // ws layout (~27 MB of 256 MiB):
    float*  kp  = (float*)d_ws;                          // 8 MB
    float*  qp  = kp + (size_t)BB * NK * HD;             // 1 MB
    float*  pO  = qp + (size_t)BB * NQ * HD;             // 8 MB
    float*  pM  = pO + (size_t)BB * 32 * 64 * 256;       // 128 KB
    float*  pL  = pM + (size_t)BB * 32 * 64;             // 128 KB
    ushort* qh  = (ushort*)(pL + (size_t)BB * 32 * 64);  // 512 KB
    ushort* ql  = qh  + 1024 * 256;
    ushort* kh  = ql  + 1024 * 256;                      // 4 MB
    ushort* kl  = kh  + 8192 * 256;                      // 4 MB
    ushort* wqh = kl  + 8192 * 256;                      // 128 KB x4
    ushort* wql = wqh + 65536;
    ushort* wkh = wql + 65536;
    ushort* wkl = wkh + 65536;

    const float SC = 2.885390081777927f;                 // 2/ln(2)

    convert_split<<<dim3(2432), 256, 0, stream>>>(queries, keys, W_q, W_k,
                                                  qh, ql, kh, kl,
                                                  wqh, wql, wkh, wkl);
    proj_mfma2<<<dim3(72, 4), 256, 0, stream>>>(qh, ql, kh, kl,
                                                wqh, wql, wkh, wkl,
                                                qp, kp, SC);
    score_pv_partial<<<dim3(BB * 32), 256, 0, stream>>>(qp, kp, values, vlens,
                                                        w_v, pO, pM, pL);
    combine_pv<<<dim3(BB * 64), 64, 0, stream>>>(pO, pM, pL, vlens, out);
}

// Round 9
// 120.210 us; speedup vs baseline: 1.2439x; 1.2439x over previous
//
#include <hip/hip_runtime.h>
#include <hip/hip_bf16.h>

#define BB 16
#define NQ 64
#define NK 512
#define HD 256   // H = QS = KS = VD = 256

typedef __attribute__((ext_vector_type(8))) short short8;
typedef __attribute__((ext_vector_type(4))) float f32x4;

__device__ __forceinline__ ushort bf16_rne(float v) {
    unsigned u = __float_as_uint(v);
    return (ushort)((u + 0x7FFFu + ((u >> 16) & 1u)) >> 16);
}
__device__ __forceinline__ float bf16_to_f(ushort h) {
    return __uint_as_float(((unsigned)h) << 16);
}

// ---------------------------------------------------------------------------
// One-shot conversion: q/k fp32 -> hi/lo bf16; W [k][n] -> hi/lo bf16 [n][k].
// ---------------------------------------------------------------------------
__global__ __launch_bounds__(256) void convert_split(
    const float* __restrict__ q, const float* __restrict__ k,
    const float* __restrict__ wq, const float* __restrict__ wk,
    ushort* __restrict__ qh, ushort* __restrict__ ql,
    ushort* __restrict__ kh, ushort* __restrict__ kl,
    ushort* __restrict__ wqh, ushort* __restrict__ wql,
    ushort* __restrict__ wkh, ushort* __restrict__ wkl)
{
    const int idx = blockIdx.x * 256 + threadIdx.x;
    if (blockIdx.x < 2304) {
        int e = idx * 4;
        const float* src; ushort *dh, *dl; int off;
        if (e < 1024 * 256) { src = q; dh = qh; dl = ql; off = e; }
        else { src = k; dh = kh; dl = kl; off = e - 1024 * 256; }
        float4 v = *(const float4*)&src[off];
        float fv[4] = {v.x, v.y, v.z, v.w};
        ushort hh[4], ll[4];
        #pragma unroll
        for (int c = 0; c < 4; ++c) {
            hh[c] = bf16_rne(fv[c]);
            ll[c] = bf16_rne(fv[c] - bf16_to_f(hh[c]));
        }
        *(ushort4*)&dh[off] = make_ushort4(hh[0], hh[1], hh[2], hh[3]);
        *(ushort4*)&dl[off] = make_ushort4(ll[0], ll[1], ll[2], ll[3]);
    } else {
        int widx = idx - 2304 * 256;
        const float* W; ushort *wh, *wl;
        if (widx < 16384) { W = wq; wh = wqh; wl = wql; }
        else { W = wk; wh = wkh; wl = wkl; widx -= 16384; }
        int n  = widx >> 6;
        int k4 = (widx & 63) * 4;
        ushort hh[4], ll[4];
        #pragma unroll
        for (int c = 0; c < 4; ++c) {
            float v = W[(k4 + c) * 256 + n];
            hh[c] = bf16_rne(v);
            ll[c] = bf16_rne(v - bf16_to_f(hh[c]));
        }
        *(ushort4*)&wh[n * 256 + k4] = make_ushort4(hh[0], hh[1], hh[2], hh[3]);
        *(ushort4*)&wl[n * 256 + k4] = make_ushort4(ll[0], ll[1], ll[2], ll[3]);
    }
}

// ---------------------------------------------------------------------------
// Split-bf16 MFMA GEMM: C = A@W (AhWh + AlWh + AhWl), * scale.  128x64 tile,
// BK=64, XOR-swizzled LDS, product-major MFMA, next-tile register prefetch.
// ---------------------------------------------------------------------------
__global__ __launch_bounds__(256, 2) void proj_mfma2(
    const ushort* __restrict__ qh, const ushort* __restrict__ ql,
    const ushort* __restrict__ kh, const ushort* __restrict__ kl,
    const ushort* __restrict__ wqh, const ushort* __restrict__ wql,
    const ushort* __restrict__ wkh, const ushort* __restrict__ wkl,
    float* __restrict__ qp, float* __restrict__ kp, float scale)
{
    __shared__ ushort AsH[128 * 64], AsL[128 * 64];
    __shared__ ushort BsH[64 * 64],  BsL[64 * 64];

    const ushort *Ah, *Al, *Bh, *Bl; float* C; int rows0;
    if (blockIdx.x < 8) { Ah = qh; Al = ql; Bh = wqh; Bl = wql; C = qp; rows0 = blockIdx.x * 128; }
    else                { Ah = kh; Al = kl; Bh = wkh; Bl = wkl; C = kp; rows0 = (blockIdx.x - 8) * 128; }
    const int cols0 = blockIdx.y * 64;

    const int t = threadIdx.x, lane = t & 63, wave = t >> 6;
    const int quad = lane >> 4, l15 = lane & 15;
    const int lr = lane >> 3;
    const int cg = (lane & 7) ^ lr;
    const int swz0 = quad ^ (l15 & 7);
    const int swz1 = (quad + 4) ^ (l15 & 7);

    f32x4 acc[2][4];
    #pragma unroll
    for (int i = 0; i < 2; ++i)
        #pragma unroll
        for (int j = 0; j < 4; ++j)
            acc[i][j] = (f32x4){0.f, 0.f, 0.f, 0.f};

    short8 rAh[4], rAl[4], rBh[2], rBl[2];
    #pragma unroll
    for (int i = 0; i < 4; ++i) {
        size_t g = (size_t)(rows0 + (wave * 4 + i) * 8 + lr) * 256 + cg * 8;
        rAh[i] = *(const short8*)&Ah[g];
        rAl[i] = *(const short8*)&Al[g];
    }
    #pragma unroll
    for (int j = 0; j < 2; ++j) {
        size_t g = (size_t)(cols0 + (wave * 2 + j) * 8 + lr) * 256 + cg * 8;
        rBh[j] = *(const short8*)&Bh[g];
        rBl[j] = *(const short8*)&Bl[g];
    }

    for (int k0 = 0; k0 < 256; k0 += 64) {
        __syncthreads();
        #pragma unroll
        for (int i = 0; i < 4; ++i) {
            int ci = (wave * 4 + i) * 64 + lane;
            *(short8*)&AsH[ci * 8] = rAh[i];
            *(short8*)&AsL[ci * 8] = rAl[i];
        }
        #pragma unroll
        for (int j = 0; j < 2; ++j) {
            int ci = (wave * 2 + j) * 64 + lane;
            *(short8*)&BsH[ci * 8] = rBh[j];
            *(short8*)&BsL[ci * 8] = rBl[j];
        }
        __syncthreads();

        if (k0 + 64 < 256) {
            #pragma unroll
            for (int i = 0; i < 4; ++i) {
                size_t g = (size_t)(rows0 + (wave * 4 + i) * 8 + lr) * 256 + k0 + 64 + cg * 8;
                rAh[i] = *(const short8*)&Ah[g];
                rAl[i] = *(const short8*)&Al[g];
            }
            #pragma unroll
            for (int j = 0; j < 2; ++j) {
                size_t g = (size_t)(cols0 + (wave * 2 + j) * 8 + lr) * 256 + k0 + 64 + cg * 8;
                rBh[j] = *(const short8*)&Bh[g];
                rBl[j] = *(const short8*)&Bl[g];
            }
        }

        #pragma unroll
        for (int ks = 0; ks < 2; ++ks) {
            const int s = ks ? swz1 : swz0;
            short8 aH[2], aL[2], bH[4], bL[4];
            #pragma unroll
            for (int ms = 0; ms < 2; ++ms) {
                int r = wave * 32 + ms * 16 + l15;
                aH[ms] = *(const short8*)&AsH[r * 64 + s * 8];
                aL[ms] = *(const short8*)&AsL[r * 64 + s * 8];
            }
            #pragma unroll
            for (int ns = 0; ns < 4; ++ns) {
                int n = ns * 16 + l15;
                bH[ns] = *(const short8*)&BsH[n * 64 + s * 8];
                bL[ns] = *(const short8*)&BsL[n * 64 + s * 8];
            }
            #pragma unroll
            for (int ms = 0; ms < 2; ++ms)
                #pragma unroll
                for (int ns = 0; ns < 4; ++ns)
                    acc[ms][ns] = __builtin_amdgcn_mfma_f32_16x16x32_bf16(aH[ms], bH[ns], acc[ms][ns], 0, 0, 0);
            #pragma unroll
            for (int ms = 0; ms < 2; ++ms)
                #pragma unroll
                for (int ns = 0; ns < 4; ++ns)
                    acc[ms][ns] = __builtin_amdgcn_mfma_f32_16x16x32_bf16(aL[ms], bH[ns], acc[ms][ns], 0, 0, 0);
            #pragma unroll
            for (int ms = 0; ms < 2; ++ms)
                #pragma unroll
                for (int ns = 0; ns < 4; ++ns)
                    acc[ms][ns] = __builtin_amdgcn_mfma_f32_16x16x32_bf16(aH[ms], bL[ns], acc[ms][ns], 0, 0, 0);
        }
    }

    #pragma unroll
    for (int ms = 0; ms < 2; ++ms) {
        int rbase = rows0 + wave * 32 + ms * 16 + quad * 4;
        #pragma unroll
        for (int ns = 0; ns < 4; ++ns) {
            int col = cols0 + ns * 16 + l15;
            #pragma unroll
            for (int r = 0; r < 4; ++r)
                C[(size_t)(rbase + r) * 256 + col] = acc[ms][ns][r] * scale;
        }
    }
}

// ---------------------------------------------------------------------------
// Segment-parallel flash partial.  Block = (b, q-pair, 64-key segment):
// grid 512x8, alive ~2300, UNIFORM cost, tiny LDS (high residency).
// q/w live in REGISTERS (eq = exp2(q) precomputed); per key-element one
// ek = exp2(k) is shared by both queries: exp2(q+k) = eq*ek  (1.5 trans per
// element instead of 2).  score = Wsum - 2*sum_h w*rcp(eq*ek + 1).
// Per-segment softmax (m,l,P) then P@V with cross-wave LDS reduce.
// Masked keys get s=-1e6 -> exp2 underflows to exact 0 (bit-exact skip).
// ---------------------------------------------------------------------------
__global__ __launch_bounds__(256) void score_pv_seg(
    const float* __restrict__ qp,      // [B*NQ, H] pre-scaled by 2/ln2
    const float* __restrict__ kp,      // [B*NK, H] pre-scaled
    const float* __restrict__ values,  // [B, NK, VD]
    const int*   __restrict__ vlens,   // [B]
    const float* __restrict__ w_v,     // [H]
    float* __restrict__ pO,            // [B][32][8][2][256]
    float* __restrict__ pM,            // [B][32][8][2]
    float* __restrict__ pL)            // [B][32][8][2]
{
    __shared__ float Ps[2][64];
    __shared__ float part[4][2][HD];

    const int b     = blockIdx.x & 15;     // batch-fastest: spreads alive blocks
    const int qpair = blockIdx.x >> 4;
    const int seg   = blockIdx.y;
    const int vl    = vlens[b];
    if (seg * 64 >= vl) return;

    const int t = threadIdx.x, lane = t & 63, wave = t >> 6;
    const int keyLoc = lane >> 4, ch = lane & 15;

    // ---- register q/w fragments: h = ch*4 + m*64 + c ----
    const float* q0 = qp + ((size_t)b * NQ + qpair * 2) * HD;
    float eqa[16], eqb[16];
    float4 wf[4];
    float Wsum = 0.f;
    #pragma unroll
    for (int m = 0; m < 4; ++m) {
        float4 a  = *(const float4*)&q0[ch * 4 + m * 64];
        float4 bq = *(const float4*)&q0[HD + ch * 4 + m * 64];
        wf[m] = *(const float4*)&w_v[ch * 4 + m * 64];
        eqa[m * 4 + 0] = __builtin_amdgcn_exp2f(a.x);
        eqa[m * 4 + 1] = __builtin_amdgcn_exp2f(a.y);
        eqa[m * 4 + 2] = __builtin_amdgcn_exp2f(a.z);
        eqa[m * 4 + 3] = __builtin_amdgcn_exp2f(a.w);
        eqb[m * 4 + 0] = __builtin_amdgcn_exp2f(bq.x);
        eqb[m * 4 + 1] = __builtin_amdgcn_exp2f(bq.y);
        eqb[m * 4 + 2] = __builtin_amdgcn_exp2f(bq.z);
        eqb[m * 4 + 3] = __builtin_amdgcn_exp2f(bq.w);
        Wsum += (wf[m].x + wf[m].y) + (wf[m].z + wf[m].w);
    }
    Wsum += __shfl_xor(Wsum, 1);
    Wsum += __shfl_xor(Wsum, 2);
    Wsum += __shfl_xor(Wsum, 4);
    Wsum += __shfl_xor(Wsum, 8);

    // ---- scores: 4 iters x (4 waves x 4 keys) = 64 keys ----
    const float* kbase = kp + ((size_t)b * NK + seg * 64) * HD;
    #pragma unroll
    for (int it = 0; it < 4; ++it) {
        const int nloc = it * 16 + wave * 4 + keyLoc;
        const float* krow = kbase + (size_t)nloc * HD + ch * 4;
        float4 kk[4];
        #pragma unroll
        for (int m = 0; m < 4; ++m) kk[m] = *(const float4*)&krow[m * 64];

        float s0 = 0.f, s1 = 0.f;
        #pragma unroll
        for (int m = 0; m < 4; ++m) {
            float kv[4]  = {kk[m].x, kk[m].y, kk[m].z, kk[m].w};
            float wv4[4] = {wf[m].x, wf[m].y, wf[m].z, wf[m].w};
            #pragma unroll
            for (int c = 0; c < 4; ++c) {
                float ek = __builtin_amdgcn_exp2f(kv[c]);
                float r0 = __builtin_amdgcn_rcpf(fmaf(eqa[m * 4 + c], ek, 1.f));
                float r1 = __builtin_amdgcn_rcpf(fmaf(eqb[m * 4 + c], ek, 1.f));
                s0 = fmaf(wv4[c], r0, s0);
                s1 = fmaf(wv4[c], r1, s1);
            }
        }
        s0 += __shfl_xor(s0, 1); s0 += __shfl_xor(s0, 2);
        s0 += __shfl_xor(s0, 4); s0 += __shfl_xor(s0, 8);
        s1 += __shfl_xor(s1, 1); s1 += __shfl_xor(s1, 2);
        s1 += __shfl_xor(s1, 4); s1 += __shfl_xor(s1, 8);
        if (ch == 0) {
            const bool masked = (seg * 64 + nloc >= vl);
            Ps[0][nloc] = masked ? -1e6f : fmaf(-2.f, s0, Wsum);
            Ps[1][nloc] = masked ? -1e6f : fmaf(-2.f, s1, Wsum);
        }
    }
    __syncthreads();

    // ---- per-segment softmax: wave 0 -> q0, wave 1 -> q1 ----
    const float L2E = 1.4426950408889634f;
    if (wave < 2) {
        float s = Ps[wave][lane];
        float m = s;
        #pragma unroll
        for (int off = 32; off; off >>= 1) m = fmaxf(m, __shfl_xor(m, off));
        float e = __builtin_amdgcn_exp2f((s - m) * L2E);
        float l = e;
        #pragma unroll
        for (int off = 32; off; off >>= 1) l += __shfl_xor(l, off);
        Ps[wave][lane] = e;
        if (lane == 0) {
            size_t mi = ((size_t)(b * 32 + qpair) * 8 + seg) * 2 + wave;
            pM[mi] = m;
            pL[mi] = l;
        }
    }
    __syncthreads();

    // ---- PV: wave w handles keys w*16..w*16+15; lane owns vd = lane*4 ----
    f32x4 acc0 = (f32x4){0.f, 0.f, 0.f, 0.f};
    f32x4 acc1 = (f32x4){0.f, 0.f, 0.f, 0.f};
    const float* vbase = values + ((size_t)b * NK + seg * 64) * HD;
    #pragma unroll
    for (int i = 0; i < 16; ++i) {
        const int k = wave * 16 + i;
        float p0 = Ps[0][k];
        float p1 = Ps[1][k];
        float4 v = *(const float4*)&vbase[(size_t)k * HD + lane * 4];
        acc0[0] = fmaf(p0, v.x, acc0[0]); acc0[1] = fmaf(p0, v.y, acc0[1]);
        acc0[2] = fmaf(p0, v.z, acc0[2]); acc0[3] = fmaf(p0, v.w, acc0[3]);
        acc1[0] = fmaf(p1, v.x, acc1[0]); acc1[1] = fmaf(p1, v.y, acc1[1]);
        acc1[2] = fmaf(p1, v.z, acc1[2]); acc1[3] = fmaf(p1, v.w, acc1[3]);
    }
    *(f32x4*)&part[wave][0][lane * 4] = acc0;
    *(f32x4*)&part[wave][1][lane * 4] = acc1;
    __syncthreads();

    if (wave < 2) {
        float4 p0 = *(const float4*)&part[0][wave][lane * 4];
        float4 p1 = *(const float4*)&part[1][wave][lane * 4];
        float4 p2 = *(const float4*)&part[2][wave][lane * 4];
        float4 p3 = *(const float4*)&part[3][wave][lane * 4];
        f32x4 o;
        o[0] = (p0.x + p1.x) + (p2.x + p3.x);
        o[1] = (p0.y + p1.y) + (p2.y + p3.y);
        o[2] = (p0.z + p1.z) + (p2.z + p3.z);
        o[3] = (p0.w + p1.w) + (p2.w + p3.w);
        size_t ob = (((size_t)(b * 32 + qpair) * 8 + seg) * 2 + wave) * 256;
        *(f32x4*)&pO[ob + lane * 4] = o;
    }
}

// ---------------------------------------------------------------------------
// Combine: block per (b,q), 256 threads (thread = one vd element).
// O = sum_i e2(m_i-m)*O_i / sum_i e2(m_i-m)*l_i over alive segs i < nc (<=8).
// ---------------------------------------------------------------------------
__global__ __launch_bounds__(256) void combine_seg(
    const float* __restrict__ pO, const float* __restrict__ pM,
    const float* __restrict__ pL, const int* __restrict__ vlens,
    float* __restrict__ out)
{
    const int b  = blockIdx.x >> 6;
    const int q  = blockIdx.x & 63;
    const int t  = threadIdx.x;
    const int vl = vlens[b];
    const int nc = (vl + 63) >> 6;
    const int qpair = q >> 1, q2 = q & 1;
    const float L2E = 1.4426950408889634f;

    const size_t base = (size_t)(b * 32 + qpair) * 8;

    float mi[8], li[8];
    float m = -3e38f;
    #pragma unroll
    for (int i = 0; i < 8; ++i) {
        if (i < nc) {
            mi[i] = pM[(base + i) * 2 + q2];
            li[i] = pL[(base + i) * 2 + q2];
            m = fmaxf(m, mi[i]);
        }
    }
    float L = 0.f, wi[8];
    #pragma unroll
    for (int i = 0; i < 8; ++i) {
        if (i < nc) {
            wi[i] = __builtin_amdgcn_exp2f((mi[i] - m) * L2E);
            L = fmaf(li[i], wi[i], L);
        }
    }
    float acc = 0.f;
    #pragma unroll
    for (int i = 0; i < 8; ++i) {
        if (i < nc) acc = fmaf(wi[i], pO[((base + i) * 2 + q2) * 256 + t], acc);
    }
    out[((size_t)(b * 64 + q)) * 256 + t] = acc * __builtin_amdgcn_rcpf(L);
}

extern "C" void kernel_launch(void* const* d_in, const int* in_sizes, int n_in,
                              void* d_out, int out_size, void* d_ws, size_t ws_size,
                              hipStream_t stream) {
    const float* queries = (const float*)d_in[0];
    const float* keys    = (const float*)d_in[1];
    const float* values  = (const float*)d_in[2];
    const int*   vlens   = (const int*)d_in[3];
    const float* W_q     = (const float*)d_in[4];
    const float* W_k     = (const float*)d_in[5];
    const float* w_v     = (const float*)d_in[6];
    float* out = (float*)d_out;

    // ws layout (~27 MB of 256 MiB):
    float*  kp  = (float*)d_ws;                          // 8 MB
    float*  qp  = kp + (size_t)BB * NK * HD;             // 1 MB
    float*  pO  = qp + (size_t)BB * NQ * HD;             // 8 MB
    float*  pM  = pO + (size_t)BB * 32 * 8 * 2 * 256;    // 32 KB
    float*  pL  = pM + (size_t)BB * 32 * 8 * 2;          // 32 KB
    ushort* qh  = (ushort*)(pL + (size_t)BB * 32 * 8 * 2);
    ushort* ql  = qh  + 1024 * 256;
    ushort* kh  = ql  + 1024 * 256;                      // 4 MB
    ushort* kl  = kh  + 8192 * 256;                      // 4 MB
    ushort* wqh = kl  + 8192 * 256;                      // 128 KB x4
    ushort* wql = wqh + 65536;
    ushort* wkh = wql + 65536;
    ushort* wkl = wkh + 65536;

    const float SC = 2.885390081777927f;                 // 2/ln(2)

    convert_split<<<dim3(2432), 256, 0, stream>>>(queries, keys, W_q, W_k,
                                                  qh, ql, kh, kl,
                                                  wqh, wql, wkh, wkl);
    proj_mfma2<<<dim3(72, 4), 256, 0, stream>>>(qh, ql, kh, kl,
                                                wqh, wql, wkh, wkl,
                                                qp, kp, SC);
    score_pv_seg<<<dim3(512, 8), 256, 0, stream>>>(qp, kp, values, vlens, w_v,
                                                   pO, pM, pL);
    combine_seg<<<dim3(BB * NQ), 256, 0, stream>>>(pO, pM, pL, vlens, out);
}

// Round 10
// 113.928 us; speedup vs baseline: 1.3125x; 1.0551x over previous
//
#include <hip/hip_runtime.h>
#include <hip/hip_bf16.h>

#define BB 16
#define NQ 64
#define NK 512
#define HD 256   // H = QS = KS = VD = 256

typedef __attribute__((ext_vector_type(8))) short short8;
typedef __attribute__((ext_vector_type(4))) float f32x4;

__device__ __forceinline__ ushort bf16_rne(float v) {
    unsigned u = __float_as_uint(v);
    return (ushort)((u + 0x7FFFu + ((u >> 16) & 1u)) >> 16);
}
__device__ __forceinline__ float bf16_to_f(ushort h) {
    return __uint_as_float(((unsigned)h) << 16);
}

// ---------------------------------------------------------------------------
// W-only conversion (tiny): W fp32 [k][n] -> hi/lo bf16 TRANSPOSED [n][k].
// 128 blocks.  Scattered L2 reads, coalesced ushort4 writes.
// ---------------------------------------------------------------------------
__global__ __launch_bounds__(256) void wconv(
    const float* __restrict__ wq, const float* __restrict__ wk,
    ushort* __restrict__ wqh, ushort* __restrict__ wql,
    ushort* __restrict__ wkh, ushort* __restrict__ wkl)
{
    int widx = blockIdx.x * 256 + threadIdx.x;     // 0..32767
    const float* W; ushort *wh, *wl;
    if (widx < 16384) { W = wq; wh = wqh; wl = wql; }
    else { W = wk; wh = wkh; wl = wkl; widx -= 16384; }
    int n  = widx >> 6;
    int k4 = (widx & 63) * 4;
    ushort hh[4], ll[4];
    #pragma unroll
    for (int c = 0; c < 4; ++c) {
        float v = W[(k4 + c) * 256 + n];
        hh[c] = bf16_rne(v);
        ll[c] = bf16_rne(v - bf16_to_f(hh[c]));
    }
    *(ushort4*)&wh[n * 256 + k4] = make_ushort4(hh[0], hh[1], hh[2], hh[3]);
    *(ushort4*)&wl[n * 256 + k4] = make_ushort4(ll[0], ll[1], ll[2], ll[3]);
}

// ---------------------------------------------------------------------------
// Projection GEMM with FUSED A-conversion: A fp32 -> hi/lo bf16 in registers
// -> XOR-swizzled LDS; W^T pre-converted (wconv).  C = AhWh + AlWh + AhWl,
// epilogue * scale.  Tile 64x64, BK=64, 576 blocks (144 x 4), 4 waves.
// Wave = 16 rows x 64 cols = 4 subtiles; 12 MFMA per ks, product-major.
// ---------------------------------------------------------------------------
__global__ __launch_bounds__(256, 2) void proj_fused(
    const float* __restrict__ queries, const float* __restrict__ keys,
    const ushort* __restrict__ wqh, const ushort* __restrict__ wql,
    const ushort* __restrict__ wkh, const ushort* __restrict__ wkl,
    float* __restrict__ qp, float* __restrict__ kp, float scale)
{
    __shared__ ushort AsH[64 * 64], AsL[64 * 64];
    __shared__ ushort BsH[64 * 64], BsL[64 * 64];

    const float* A; const ushort *Bh, *Bl; float* C; int rows0;
    const int bx = blockIdx.x;
    if (bx < 16) { A = queries; Bh = wqh; Bl = wql; C = qp; rows0 = bx * 64; }
    else         { A = keys;    Bh = wkh; Bl = wkl; C = kp; rows0 = (bx - 16) * 64; }
    const int cols0 = blockIdx.y * 64;

    const int t = threadIdx.x, lane = t & 63, wave = t >> 6;
    const int quad = lane >> 4, l15 = lane & 15;
    const int sr  = t >> 2;          // staging row / n: 0..63
    const int sc2 = (t & 3) * 2;     // chunk pair base: 0,2,4,6

    f32x4 acc[4];
    #pragma unroll
    for (int j = 0; j < 4; ++j) acc[j] = (f32x4){0.f, 0.f, 0.f, 0.f};

    for (int k0 = 0; k0 < 256; k0 += 64) {
        // global loads: A fp32 (16 elems), W^T bf16 hi/lo (2 chunks each)
        const float* arow = &A[(size_t)(rows0 + sr) * 256 + k0 + sc2 * 8];
        float4 a0 = *(const float4*)&arow[0];
        float4 a1 = *(const float4*)&arow[4];
        float4 a2 = *(const float4*)&arow[8];
        float4 a3 = *(const float4*)&arow[12];
        const ushort* bhp = &Bh[(size_t)(cols0 + sr) * 256 + k0 + sc2 * 8];
        const ushort* blp = &Bl[(size_t)(cols0 + sr) * 256 + k0 + sc2 * 8];
        short8 b0h = *(const short8*)&bhp[0];
        short8 b1h = *(const short8*)&bhp[8];
        short8 b0l = *(const short8*)&blp[0];
        short8 b1l = *(const short8*)&blp[8];

        __syncthreads();   // previous tile's compute done

        // convert A to hi/lo bf16, pack
        float av[16] = {a0.x, a0.y, a0.z, a0.w, a1.x, a1.y, a1.z, a1.w,
                        a2.x, a2.y, a2.z, a2.w, a3.x, a3.y, a3.z, a3.w};
        short8 ah0, ah1, al0, al1;
        #pragma unroll
        for (int e = 0; e < 8; ++e) {
            ushort h0 = bf16_rne(av[e]);
            ushort h1 = bf16_rne(av[8 + e]);
            ah0[e] = (short)h0;
            ah1[e] = (short)h1;
            al0[e] = (short)bf16_rne(av[e] - bf16_to_f(h0));
            al1[e] = (short)bf16_rne(av[8 + e] - bf16_to_f(h1));
        }
        // XOR-swizzled LDS stores (chunk slot = c ^ (row&7))
        {
            int s0 = sr * 8 + ((sc2 + 0) ^ (sr & 7));
            int s1 = sr * 8 + ((sc2 + 1) ^ (sr & 7));
            *(short8*)&AsH[s0 * 8] = ah0;
            *(short8*)&AsH[s1 * 8] = ah1;
            *(short8*)&AsL[s0 * 8] = al0;
            *(short8*)&AsL[s1 * 8] = al1;
            *(short8*)&BsH[s0 * 8] = b0h;
            *(short8*)&BsH[s1 * 8] = b1h;
            *(short8*)&BsL[s0 * 8] = b0l;
            *(short8*)&BsL[s1 * 8] = b1l;
        }
        __syncthreads();

        #pragma unroll
        for (int ks = 0; ks < 2; ++ks) {
            const int c = ks * 4 + quad;
            short8 aH, aL, bH[4], bL[4];
            {
                int r = wave * 16 + l15;
                int slot = r * 8 + (c ^ (r & 7));
                aH = *(const short8*)&AsH[slot * 8];
                aL = *(const short8*)&AsL[slot * 8];
            }
            #pragma unroll
            for (int ns = 0; ns < 4; ++ns) {
                int n = ns * 16 + l15;
                int slot = n * 8 + (c ^ (n & 7));
                bH[ns] = *(const short8*)&BsH[slot * 8];
                bL[ns] = *(const short8*)&BsL[slot * 8];
            }
            #pragma unroll
            for (int ns = 0; ns < 4; ++ns)
                acc[ns] = __builtin_amdgcn_mfma_f32_16x16x32_bf16(aH, bH[ns], acc[ns], 0, 0, 0);
            #pragma unroll
            for (int ns = 0; ns < 4; ++ns)
                acc[ns] = __builtin_amdgcn_mfma_f32_16x16x32_bf16(aL, bH[ns], acc[ns], 0, 0, 0);
            #pragma unroll
            for (int ns = 0; ns < 4; ++ns)
                acc[ns] = __builtin_amdgcn_mfma_f32_16x16x32_bf16(aH, bL[ns], acc[ns], 0, 0, 0);
        }
    }

    // epilogue: C/D col=lane&15, row=quad*4+reg
    const int rbase = rows0 + wave * 16 + quad * 4;
    #pragma unroll
    for (int ns = 0; ns < 4; ++ns) {
        int col = cols0 + ns * 16 + l15;
        #pragma unroll
        for (int r = 0; r < 4; ++r)
            C[(size_t)(rbase + r) * 256 + col] = acc[ns][r] * scale;
    }
}

// ---------------------------------------------------------------------------
// Segment flash partial, qtile=8.  Block = (b, q-tile of 8, 64-key segment):
// grid 128x8, alive ~576, 45 KB LDS (3 blocks/CU cap).  k+V read-amp = 8x
// total ~72 MB (vs 32x/290 MB at qtile=2).  eq=exp2(q) staged in LDS
// (broadcast reads); one ek=exp2(k) serves 8 queries (1.125 trans/elem).
// Coalesced k loads: 4 lanes per key cover one 64B line per instr.
// Masked keys -> s=-1e6 -> exp2 underflows to exact 0 (bit-exact skip).
// ---------------------------------------------------------------------------
__global__ __launch_bounds__(256) void score_pv_seg2(
    const float* __restrict__ qp,      // [B*NQ, H] pre-scaled by 2/ln2
    const float* __restrict__ kp,      // [B*NK, H] pre-scaled
    const float* __restrict__ values,  // [B, NK, VD]
    const int*   __restrict__ vlens,   // [B]
    const float* __restrict__ w_v,     // [H]
    float* __restrict__ pO,            // [B][8qt][8seg][8q][256]
    float* __restrict__ pM,            // [B][8qt][8seg][8q]
    float* __restrict__ pL)            // [B][8qt][8seg][8q]
{
    __shared__ float eq[8][260];
    __shared__ float wv[HD];
    __shared__ float Ps[8][66];
    __shared__ float part[4][8][260];

    const int b   = blockIdx.x & 15;
    const int qt  = blockIdx.x >> 4;    // 0..7
    const int seg = blockIdx.y;         // 0..7
    const int vl  = vlens[b];
    if (seg * 64 >= vl) return;

    const int t = threadIdx.x, lane = t & 63, wave = t >> 6;

    // stage eq = exp2(q) for 8 rows, and w
    const float* qsrc = qp + ((size_t)b * NQ + qt * 8) * HD;
    #pragma unroll
    for (int i = 0; i < 2; ++i) {
        int idx = i * 256 + t;           // 0..511 float4s
        int row = idx >> 6, c4 = (idx & 63) * 4;
        float4 v = *(const float4*)&qsrc[(size_t)row * HD + c4];
        eq[row][c4 + 0] = __builtin_amdgcn_exp2f(v.x);
        eq[row][c4 + 1] = __builtin_amdgcn_exp2f(v.y);
        eq[row][c4 + 2] = __builtin_amdgcn_exp2f(v.z);
        eq[row][c4 + 3] = __builtin_amdgcn_exp2f(v.w);
    }
    if (t < 64) *(float4*)&wv[t * 4] = *(const float4*)&w_v[t * 4];
    __syncthreads();

    // Wsum
    float Wsum;
    {
        float ws = wv[lane] + wv[lane + 64] + wv[lane + 128] + wv[lane + 192];
        #pragma unroll
        for (int off = 32; off; off >>= 1) ws += __shfl_xor(ws, off);
        Wsum = ws;
    }

    // ---- scores: lane -> (key = wave*16 + lane>>2, ch = lane&3) ----
    const int key = wave * 16 + (lane >> 2);
    const int ch  = lane & 3;
    const int kg  = seg * 64 + key;
    const float* krow = kp + ((size_t)b * NK + kg) * HD + ch * 4;

    float s[8] = {0.f, 0.f, 0.f, 0.f, 0.f, 0.f, 0.f, 0.f};
    #pragma unroll
    for (int j = 0; j < 16; ++j) {
        const int h = j * 16 + ch * 4;
        float4 k4 = *(const float4*)&krow[j * 16];
        float4 w4 = *(const float4*)&wv[h];
        float ek0 = __builtin_amdgcn_exp2f(k4.x);
        float ek1 = __builtin_amdgcn_exp2f(k4.y);
        float ek2 = __builtin_amdgcn_exp2f(k4.z);
        float ek3 = __builtin_amdgcn_exp2f(k4.w);
        #pragma unroll
        for (int qi = 0; qi < 8; ++qi) {
            float4 q4 = *(const float4*)&eq[qi][h];   // LDS broadcast
            float t0 = fmaf(w4.x, __builtin_amdgcn_rcpf(fmaf(q4.x, ek0, 1.f)), s[qi]);
            t0 = fmaf(w4.y, __builtin_amdgcn_rcpf(fmaf(q4.y, ek1, 1.f)), t0);
            t0 = fmaf(w4.z, __builtin_amdgcn_rcpf(fmaf(q4.z, ek2, 1.f)), t0);
            s[qi] = fmaf(w4.w, __builtin_amdgcn_rcpf(fmaf(q4.w, ek3, 1.f)), t0);
        }
    }
    #pragma unroll
    for (int qi = 0; qi < 8; ++qi) {
        s[qi] += __shfl_xor(s[qi], 1);
        s[qi] += __shfl_xor(s[qi], 2);
    }
    if (ch == 0) {
        const bool masked = (kg >= vl);
        #pragma unroll
        for (int qi = 0; qi < 8; ++qi)
            Ps[qi][key] = masked ? -1e6f : fmaf(-2.f, s[qi], Wsum);
    }
    __syncthreads();

    // ---- per-segment softmax: wave handles q rows wave*2, wave*2+1 ----
    const float L2E = 1.4426950408889634f;
    #pragma unroll
    for (int r = 0; r < 2; ++r) {
        const int row = wave * 2 + r;
        float sv = Ps[row][lane];
        float m = sv;
        #pragma unroll
        for (int off = 32; off; off >>= 1) m = fmaxf(m, __shfl_xor(m, off));
        float e = __builtin_amdgcn_exp2f((sv - m) * L2E);
        float l = e;
        #pragma unroll
        for (int off = 32; off; off >>= 1) l += __shfl_xor(l, off);
        Ps[row][lane] = e;
        if (lane == 0) {
            size_t mi = (((size_t)(b * 8 + qt) * 8 + seg)) * 8 + row;
            pM[mi] = m;
            pL[mi] = l;
        }
    }
    __syncthreads();

    // ---- PV: wave handles its 16 keys; lane owns vd = lane*4 ----
    f32x4 acc[8];
    #pragma unroll
    for (int qi = 0; qi < 8; ++qi) acc[qi] = (f32x4){0.f, 0.f, 0.f, 0.f};
    const float* vbase = values + ((size_t)b * NK + seg * 64 + wave * 16) * HD;
    #pragma unroll
    for (int i = 0; i < 16; ++i) {
        float4 v = *(const float4*)&vbase[(size_t)i * HD + lane * 4];
        #pragma unroll
        for (int qi = 0; qi < 8; ++qi) {
            float p = Ps[qi][wave * 16 + i];          // LDS broadcast
            acc[qi][0] = fmaf(p, v.x, acc[qi][0]);
            acc[qi][1] = fmaf(p, v.y, acc[qi][1]);
            acc[qi][2] = fmaf(p, v.z, acc[qi][2]);
            acc[qi][3] = fmaf(p, v.w, acc[qi][3]);
        }
    }
    #pragma unroll
    for (int qi = 0; qi < 8; ++qi)
        *(f32x4*)&part[wave][qi][lane * 4] = acc[qi];
    __syncthreads();

    // ---- cross-wave reduce + store partials ----
    const size_t ob = (((size_t)(b * 8 + qt) * 8 + seg)) * 8 * 256;
    #pragma unroll
    for (int i = 0; i < 2; ++i) {
        int idx = i * 256 + t;           // 0..511
        int qi = idx >> 6, c4 = (idx & 63) * 4;
        float4 p0 = *(const float4*)&part[0][qi][c4];
        float4 p1 = *(const float4*)&part[1][qi][c4];
        float4 p2 = *(const float4*)&part[2][qi][c4];
        float4 p3 = *(const float4*)&part[3][qi][c4];
        float4 o;
        o.x = (p0.x + p1.x) + (p2.x + p3.x);
        o.y = (p0.y + p1.y) + (p2.y + p3.y);
        o.z = (p0.z + p1.z) + (p2.z + p3.z);
        o.w = (p0.w + p1.w) + (p2.w + p3.w);
        *(float4*)&pO[ob + (size_t)qi * 256 + c4] = o;
    }
}

// ---------------------------------------------------------------------------
// Combine: block per (b,q), 256 threads (one vd element each).
// O = sum_i e2(m_i-m)*O_i / sum_i e2(m_i-m)*l_i, i < nc (<=8 segs).
// ---------------------------------------------------------------------------
__global__ __launch_bounds__(256) void combine_seg2(
    const float* __restrict__ pO, const float* __restrict__ pM,
    const float* __restrict__ pL, const int* __restrict__ vlens,
    float* __restrict__ out)
{
    const int b  = blockIdx.x >> 6;
    const int q  = blockIdx.x & 63;
    const int t  = threadIdx.x;
    const int vl = vlens[b];
    const int nc = (vl + 63) >> 6;
    const int qt = q >> 3, qi = q & 7;
    const float L2E = 1.4426950408889634f;

    const size_t base = (size_t)(b * 8 + qt) * 8;   // + seg, then *8 + qi

    float mi[8], li[8];
    float m = -3e38f;
    #pragma unroll
    for (int i = 0; i < 8; ++i) {
        if (i < nc) {
            mi[i] = pM[(base + i) * 8 + qi];
            li[i] = pL[(base + i) * 8 + qi];
            m = fmaxf(m, mi[i]);
        }
    }
    float L = 0.f, wi[8];
    #pragma unroll
    for (int i = 0; i < 8; ++i) {
        if (i < nc) {
            wi[i] = __builtin_amdgcn_exp2f((mi[i] - m) * L2E);
            L = fmaf(li[i], wi[i], L);
        }
    }
    float acc = 0.f;
    #pragma unroll
    for (int i = 0; i < 8; ++i) {
        if (i < nc) acc = fmaf(wi[i], pO[((base + i) * 8 + qi) * 256 + t], acc);
    }
    out[((size_t)(b * 64 + q)) * 256 + t] = acc * __builtin_amdgcn_rcpf(L);
}

extern "C" void kernel_launch(void* const* d_in, const int* in_sizes, int n_in,
                              void* d_out, int out_size, void* d_ws, size_t ws_size,
                              hipStream_t stream) {
    const float* queries = (const float*)d_in[0];
    const float* keys    = (const float*)d_in[1];
    const float* values  = (const float*)d_in[2];
    const int*   vlens   = (const int*)d_in[3];
    const float* W_q     = (const float*)d_in[4];
    const float* W_k     = (const float*)d_in[5];
    const float* w_v     = (const float*)d_in[6];
    float* out = (float*)d_out;

    // ws layout (~17.5 MB of 256 MiB):
    float*  kp  = (float*)d_ws;                          // 8 MB
    float*  qp  = kp + (size_t)BB * NK * HD;             // 1 MB
    float*  pO  = qp + (size_t)BB * NQ * HD;             // 8 MB
    float*  pM  = pO + (size_t)BB * 8 * 8 * 8 * 256;     // 32 KB
    float*  pL  = pM + (size_t)BB * 8 * 8 * 8;           // 32 KB
    ushort* wqh = (ushort*)(pL + (size_t)BB * 8 * 8 * 8);
    ushort* wql = wqh + 65536;
    ushort* wkh = wql + 65536;
    ushort* wkl = wkh + 65536;

    const float SC = 2.885390081777927f;                 // 2/ln(2)

    wconv<<<dim3(128), 256, 0, stream>>>(W_q, W_k, wqh, wql, wkh, wkl);
    proj_fused<<<dim3(144, 4), 256, 0, stream>>>(queries, keys,
                                                 wqh, wql, wkh, wkl,
                                                 qp, kp, SC);
    score_pv_seg2<<<dim3(128, 8), 256, 0, stream>>>(qp, kp, values, vlens, w_v,
                                                    pO, pM, pL);
    combine_seg2<<<dim3(BB * NQ), 256, 0, stream>>>(pO, pM, pL, vlens, out);
}